// Round 4
// baseline (834.426 us; speedup 1.0000x reference)
//
#include <hip/hip_runtime.h>

#define N_NODES 50000
#define N_EDGES 1600000
#define F 32
#define NB ((N_NODES + 63) >> 6)      // 782 buckets of 64 nodes
#define FILL_CHUNK 16384

// ---------- coarse bucket histogram (LDS-privatized) ----------
__global__ __launch_bounds__(256)
void k_bhist(const int* __restrict__ dst, int* __restrict__ bhist) {
    __shared__ int lh[NB];
    for (int i = threadIdx.x; i < NB; i += 256) lh[i] = 0;
    __syncthreads();
    for (int e = blockIdx.x * blockDim.x + threadIdx.x; e < N_EDGES;
         e += gridDim.x * blockDim.x)
        atomicAdd(&lh[dst[e] >> 6], 1);
    __syncthreads();
    for (int i = threadIdx.x; i < NB; i += 256)
        if (lh[i]) atomicAdd(&bhist[i], lh[i]);
}

// ---------- scan 782 bucket counts -> offsets + fill cursors ----------
__global__ __launch_bounds__(1024)
void k_bscan(const int* __restrict__ bhist,
             int* __restrict__ bucket_off,
             int* __restrict__ cursor) {
    __shared__ int s[1024];
    int t = threadIdx.x;
    int v = (t < NB) ? bhist[t] : 0;
    s[t] = v;
    __syncthreads();
    for (int off = 1; off < 1024; off <<= 1) {
        int u = (t >= off) ? s[t - off] : 0;
        __syncthreads();
        s[t] += u;
        __syncthreads();
    }
    if (t < NB) {
        int ex = s[t] - v;          // exclusive
        bucket_off[t] = ex;
        cursor[t] = ex;
    }
    if (t == NB - 1) bucket_off[NB] = s[t];
}

// ---------- bin edges into bucket runs; pack local node id ----------
// Each block owns contiguous runs it reserved -> same-XCD L2, full-line writes.
__global__ __launch_bounds__(256)
void k_bucket_fill(const int* __restrict__ dst,
                   int* __restrict__ cursor,
                   int* __restrict__ coarse) {
    __shared__ int lh[NB];
    __shared__ int gb[NB];
    int lo = blockIdx.x * FILL_CHUNK;
    int hi = min(lo + FILL_CHUNK, N_EDGES);

    for (int i = threadIdx.x; i < NB; i += 256) lh[i] = 0;
    __syncthreads();
    for (int e = lo + threadIdx.x; e < hi; e += 256)
        atomicAdd(&lh[dst[e] >> 6], 1);
    __syncthreads();
    for (int i = threadIdx.x; i < NB; i += 256) {
        gb[i] = atomicAdd(&cursor[i], lh[i]);
        lh[i] = 0;                  // reuse as rank counter
    }
    __syncthreads();
    for (int e = lo + threadIdx.x; e < hi; e += 256) {
        int d = dst[e];
        int b = d >> 6;
        int r = atomicAdd(&lh[b], 1);
        coarse[gb[b] + r] = e | ((d & 63) << 21);   // e < 2^21
    }
}

// ---------- stage 1+2: per-bucket LDS accumulation -> node_mean ----------
// 256 threads = 32 edges x 8 float4-quads per iteration.
__global__ __launch_bounds__(256)
void k_bucket_mean(const float* __restrict__ inputs,
                   const int* __restrict__ coarse,
                   const int* __restrict__ bucket_off,
                   float* __restrict__ node_mean) {
    __shared__ float acc[64][33];   // +1 pad: bank = (local + 4q + j) % 32
    __shared__ int cnt[64];
    int tid = threadIdx.x;
    for (int i = tid; i < 64 * 33; i += 256) ((float*)acc)[i] = 0.f;
    if (tid < 64) cnt[tid] = 0;
    __syncthreads();

    int b = blockIdx.x;
    int lo = bucket_off[b], hi = bucket_off[b + 1];
    int eslot = tid >> 3, q = tid & 7;

    for (int i = lo + eslot; i < hi; i += 32) {
        int entry = coarse[i];
        int e = entry & 0x1FFFFF;
        int local = entry >> 21;
        float4 v = *reinterpret_cast<const float4*>(&inputs[(size_t)e * F + q * 4]);
        atomicAdd(&acc[local][q * 4 + 0], v.x);
        atomicAdd(&acc[local][q * 4 + 1], v.y);
        atomicAdd(&acc[local][q * 4 + 2], v.z);
        atomicAdd(&acc[local][q * 4 + 3], v.w);
        if (q == 0) atomicAdd(&cnt[local], 1);
    }
    __syncthreads();

    int nbase = b << 6;
    int nLocal = min(64, N_NODES - nbase);
    for (int idx = tid; idx < nLocal * 32; idx += 256) {
        int n = idx >> 5, f = idx & 31;
        float r = 1.0f / fmaxf((float)cnt[n], 1.0f);
        node_mean[(size_t)(nbase + n) * F + f] = acc[n][f] * r;
    }
}

// ---------- stage 3 + projection fused: node_p = (sum mean[src]) @ W^T ----------
__global__ __launch_bounds__(256)
void k_bucket_h(const int* __restrict__ src,
                const int* __restrict__ coarse,
                const int* __restrict__ bucket_off,
                const float* __restrict__ node_mean,
                const float* __restrict__ W,
                float* __restrict__ node_p) {
    __shared__ float acc[64][33];
    __shared__ float Wl[32][33];
    int tid = threadIdx.x;
    for (int i = tid; i < 64 * 33; i += 256) ((float*)acc)[i] = 0.f;
    for (int i = tid; i < 1024; i += 256) Wl[i >> 5][i & 31] = W[i];
    __syncthreads();

    int b = blockIdx.x;
    int lo = bucket_off[b], hi = bucket_off[b + 1];
    int eslot = tid >> 3, q = tid & 7;

    for (int i = lo + eslot; i < hi; i += 32) {
        int entry = coarse[i];
        int e = entry & 0x1FFFFF;
        int local = entry >> 21;
        int s = src[e];
        float4 v = *reinterpret_cast<const float4*>(&node_mean[(size_t)s * F + q * 4]);
        atomicAdd(&acc[local][q * 4 + 0], v.x);
        atomicAdd(&acc[local][q * 4 + 1], v.y);
        atomicAdd(&acc[local][q * 4 + 2], v.z);
        atomicAdd(&acc[local][q * 4 + 3], v.w);
    }
    __syncthreads();

    int nbase = b << 6;
    int nLocal = min(64, N_NODES - nbase);
    for (int idx = tid; idx < nLocal * 32; idx += 256) {
        int n = idx >> 5, o = idx & 31;
        float sacc = 0.f;
        #pragma unroll
        for (int i = 0; i < 32; ++i) sacc += acc[n][i] * Wl[o][i];
        node_p[(size_t)(nbase + n) * F + o] = sacc;
    }
}

// ---------- stage 4: out[e] = 0.5*(node_p[src] + node_p[dst]) + b ----------
__global__ void k_edge_out(const int* __restrict__ src,
                           const int* __restrict__ dst,
                           const float* __restrict__ node_p,
                           const float* __restrict__ b,
                           float* __restrict__ out) {
    int tid = blockIdx.x * blockDim.x + threadIdx.x;   // e*8 + q
    if (tid >= N_EDGES * 8) return;
    int e = tid >> 3;
    int q = tid & 7;
    int s = src[e];
    int d = dst[e];

    const float4 a  = *reinterpret_cast<const float4*>(&node_p[(size_t)s * F + q * 4]);
    const float4 c  = *reinterpret_cast<const float4*>(&node_p[(size_t)d * F + q * 4]);
    const float4 bb = *reinterpret_cast<const float4*>(&b[q * 4]);

    float4 r;
    r.x = 0.5f * (a.x + c.x) + bb.x;
    r.y = 0.5f * (a.y + c.y) + bb.y;
    r.z = 0.5f * (a.z + c.z) + bb.z;
    r.w = 0.5f * (a.w + c.w) + bb.w;

    *reinterpret_cast<float4*>(&out[(size_t)e * F + q * 4]) = r;
}

extern "C" void kernel_launch(void* const* d_in, const int* in_sizes, int n_in,
                              void* d_out, int out_size, void* d_ws, size_t ws_size,
                              hipStream_t stream) {
    const float* inputs = (const float*)d_in[0];
    const int*   src    = (const int*)d_in[1];
    const int*   dst    = (const int*)d_in[2];
    const float* W      = (const float*)d_in[3];
    const float* b      = (const float*)d_in[4];
    float* out = (float*)d_out;

    // Workspace layout
    int* bhist      = (int*)d_ws;                    // NB
    int* bucket_off = bhist + NB;                    // NB+1
    int* cursor     = bucket_off + NB + 1;           // NB
    int* coarse     = cursor + NB;                   // E (packed e | local<<21)
    float* node_mean = (float*)(coarse + N_EDGES);   // N*F
    float* node_p    = node_mean + (size_t)N_NODES * F;  // N*F

    hipMemsetAsync(bhist, 0, NB * sizeof(int), stream);

    k_bhist<<<256, 256, 0, stream>>>(dst, bhist);
    k_bscan<<<1, 1024, 0, stream>>>(bhist, bucket_off, cursor);
    k_bucket_fill<<<(N_EDGES + FILL_CHUNK - 1) / FILL_CHUNK, 256, 0, stream>>>(
        dst, cursor, coarse);
    k_bucket_mean<<<NB, 256, 0, stream>>>(inputs, coarse, bucket_off, node_mean);
    k_bucket_h<<<NB, 256, 0, stream>>>(src, coarse, bucket_off, node_mean, W, node_p);
    k_edge_out<<<(N_EDGES * 8 + 255) / 256, 256, 0, stream>>>(src, dst, node_p, b, out);
}

// Round 5
// 288.190 us; speedup vs baseline: 2.8954x; 2.8954x over previous
//
#include <hip/hip_runtime.h>

#define N_NODES 50000
#define N_EDGES 1600000
#define F 32
#define BSH 7                               // 128 nodes per bucket
#define BSIZE (1 << BSH)
#define NB ((N_NODES + BSIZE - 1) >> BSH)   // 391 buckets
#define FILL_CHUNK 8192
#define EMASK 0x1FFFFF

// ---------- coarse bucket histogram (LDS-privatized) ----------
__global__ __launch_bounds__(256)
void k_bhist(const int* __restrict__ dst, int* __restrict__ bhist) {
    __shared__ int lh[NB];
    for (int i = threadIdx.x; i < NB; i += 256) lh[i] = 0;
    __syncthreads();
    for (int e = blockIdx.x * blockDim.x + threadIdx.x; e < N_EDGES;
         e += gridDim.x * blockDim.x)
        atomicAdd(&lh[dst[e] >> BSH], 1);
    __syncthreads();
    for (int i = threadIdx.x; i < NB; i += 256)
        if (lh[i]) atomicAdd(&bhist[i], lh[i]);
}

// ---------- scan 391 bucket counts -> offsets + fill cursors ----------
__global__ __launch_bounds__(512)
void k_bscan(const int* __restrict__ bhist,
             int* __restrict__ bucket_off,
             int* __restrict__ cursor) {
    __shared__ int s[512];
    int t = threadIdx.x;
    int v = (t < NB) ? bhist[t] : 0;
    s[t] = v;
    __syncthreads();
    for (int off = 1; off < 512; off <<= 1) {
        int u = (t >= off) ? s[t - off] : 0;
        __syncthreads();
        s[t] += u;
        __syncthreads();
    }
    if (t < NB) {
        int ex = s[t] - v;
        bucket_off[t] = ex;
        cursor[t] = ex;
    }
    if (t == NB - 1) bucket_off[NB] = s[t];
}

// ---------- phase A: bin edges into bucket runs (coalesced run writes) ----------
__global__ __launch_bounds__(256)
void k_coarse_fill(const int* __restrict__ dst,
                   int* __restrict__ cursor,
                   int* __restrict__ coarse) {
    __shared__ int lh[NB];
    __shared__ int gb[NB];
    int lo = blockIdx.x * FILL_CHUNK;
    int hi = min(lo + FILL_CHUNK, N_EDGES);

    for (int i = threadIdx.x; i < NB; i += 256) lh[i] = 0;
    __syncthreads();
    for (int e = lo + threadIdx.x; e < hi; e += 256)
        atomicAdd(&lh[dst[e] >> BSH], 1);
    __syncthreads();
    for (int i = threadIdx.x; i < NB; i += 256) {
        gb[i] = atomicAdd(&cursor[i], lh[i]);
        lh[i] = 0;                  // reuse as rank counter
    }
    __syncthreads();
    for (int e = lo + threadIdx.x; e < hi; e += 256) {
        int d = dst[e];
        int bk = d >> BSH;
        int r = atomicAdd(&lh[bk], 1);
        coarse[gb[bk] + r] = e | ((d & (BSIZE - 1)) << 21);   // e < 2^21
    }
}

// ---------- phase B: exact CSR within each 128-node bucket ----------
// All scattered writes land in a ~16KB window owned by this block.
// Also emits row_off (derived locally, no global hist/scan over 50K)
// and src_sorted (so stage 3 reads coalesced).
__global__ __launch_bounds__(256)
void k_exact_fill(const int* __restrict__ coarse,
                  const int* __restrict__ bucket_off,
                  const int* __restrict__ src,
                  int* __restrict__ row_off,
                  int* __restrict__ eid,
                  int* __restrict__ src_sorted) {
    __shared__ int cnt[BSIZE];
    __shared__ int s[BSIZE];
    __shared__ int cur[BSIZE];
    int tid = threadIdx.x;
    int b = blockIdx.x;
    int lo = bucket_off[b], hi = bucket_off[b + 1];

    if (tid < BSIZE) cnt[tid] = 0;
    __syncthreads();
    for (int i = lo + tid; i < hi; i += 256)
        atomicAdd(&cnt[(coarse[i] >> 21) & (BSIZE - 1)], 1);
    __syncthreads();
    if (tid < BSIZE) s[tid] = cnt[tid];
    __syncthreads();
    for (int off = 1; off < BSIZE; off <<= 1) {
        int v = 0;
        if (tid < BSIZE && tid >= off) v = s[tid - off];
        __syncthreads();
        if (tid < BSIZE) s[tid] += v;
        __syncthreads();
    }
    int nbase = b << BSH;
    if (tid < BSIZE) {
        int base = lo + s[tid] - cnt[tid];   // exclusive scan + bucket base
        cur[tid] = base;
        if (nbase + tid < N_NODES) row_off[nbase + tid] = base;
    }
    if (b == NB - 1 && tid == 0) row_off[N_NODES] = N_EDGES;
    __syncthreads();
    for (int i = lo + tid; i < hi; i += 256) {
        int entry = coarse[i];
        int l = (entry >> 21) & (BSIZE - 1);
        int e = entry & EMASK;
        int p = atomicAdd(&cur[l], 1);
        eid[p] = e;
        src_sorted[p] = src[e];
    }
}

// ---------- stage 1+2: node_mean via per-node wave reduce (no atomics) ----------
__global__ __launch_bounds__(256)
void k_node_mean(const float* __restrict__ inputs,
                 const int* __restrict__ eid,
                 const int* __restrict__ row_off,
                 float* __restrict__ node_mean) {
    int wave = (blockIdx.x * blockDim.x + threadIdx.x) >> 6;
    if (wave >= N_NODES) return;
    int lane  = threadIdx.x & 63;
    int eslot = lane >> 3;       // 0..7
    int q     = lane & 7;        // float4 quad

    int s0 = row_off[wave];
    int s1 = row_off[wave + 1];

    float4 acc = {0.f, 0.f, 0.f, 0.f};
    for (int i = s0 + eslot; i < s1; i += 8) {
        int e = eid[i];
        float4 v = *reinterpret_cast<const float4*>(&inputs[(size_t)e * F + q * 4]);
        acc.x += v.x; acc.y += v.y; acc.z += v.z; acc.w += v.w;
    }
    #pragma unroll
    for (int m = 8; m <= 32; m <<= 1) {
        acc.x += __shfl_xor(acc.x, m);
        acc.y += __shfl_xor(acc.y, m);
        acc.z += __shfl_xor(acc.z, m);
        acc.w += __shfl_xor(acc.w, m);
    }
    if (eslot == 0) {
        float r = 1.0f / fmaxf((float)(s1 - s0), 1.0f);
        float4 o = {acc.x * r, acc.y * r, acc.z * r, acc.w * r};
        *reinterpret_cast<float4*>(&node_mean[(size_t)wave * F + q * 4]) = o;
    }
}

// ---------- stage 3: node_h via per-node wave reduce over src_sorted ----------
__global__ __launch_bounds__(256)
void k_node_h(const int* __restrict__ src_sorted,
              const int* __restrict__ row_off,
              const float* __restrict__ node_mean,
              float* __restrict__ node_h) {
    int wave = (blockIdx.x * blockDim.x + threadIdx.x) >> 6;
    if (wave >= N_NODES) return;
    int lane  = threadIdx.x & 63;
    int eslot = lane >> 3;
    int q     = lane & 7;

    int s0 = row_off[wave];
    int s1 = row_off[wave + 1];

    float4 acc = {0.f, 0.f, 0.f, 0.f};
    for (int i = s0 + eslot; i < s1; i += 8) {
        int s = src_sorted[i];
        float4 v = *reinterpret_cast<const float4*>(&node_mean[(size_t)s * F + q * 4]);
        acc.x += v.x; acc.y += v.y; acc.z += v.z; acc.w += v.w;
    }
    #pragma unroll
    for (int m = 8; m <= 32; m <<= 1) {
        acc.x += __shfl_xor(acc.x, m);
        acc.y += __shfl_xor(acc.y, m);
        acc.z += __shfl_xor(acc.z, m);
        acc.w += __shfl_xor(acc.w, m);
    }
    if (eslot == 0) {
        *reinterpret_cast<float4*>(&node_h[(size_t)wave * F + q * 4]) = acc;
    }
}

// ---------- stage 3.5: node_p = node_h @ W^T ----------
__global__ __launch_bounds__(256)
void k_project(const float* __restrict__ node_h,
               const float* __restrict__ W,
               float* __restrict__ node_p) {
    __shared__ float Wl[32][33];
    __shared__ float hr[8][32];

    int tid = threadIdx.x;
    #pragma unroll
    for (int i = tid; i < 1024; i += 256) {
        Wl[i >> 5][i & 31] = W[i];
    }

    int ln = tid >> 5;
    int o  = tid & 31;
    int n  = blockIdx.x * 8 + ln;

    float v = 0.0f;
    if (n < N_NODES) v = node_h[(size_t)n * F + o];
    hr[ln][o] = v;
    __syncthreads();

    if (n < N_NODES) {
        float acc = 0.0f;
        #pragma unroll
        for (int i = 0; i < 32; ++i) {
            acc += hr[ln][i] * Wl[o][i];
        }
        node_p[(size_t)n * F + o] = acc;
    }
}

// ---------- stage 4: out[e] = 0.5*(node_p[src] + node_p[dst]) + b ----------
__global__ void k_edge_out(const int* __restrict__ src,
                           const int* __restrict__ dst,
                           const float* __restrict__ node_p,
                           const float* __restrict__ b,
                           float* __restrict__ out) {
    int tid = blockIdx.x * blockDim.x + threadIdx.x;   // e*8 + q
    if (tid >= N_EDGES * 8) return;
    int e = tid >> 3;
    int q = tid & 7;
    int s = src[e];
    int d = dst[e];

    const float4 a  = *reinterpret_cast<const float4*>(&node_p[(size_t)s * F + q * 4]);
    const float4 c  = *reinterpret_cast<const float4*>(&node_p[(size_t)d * F + q * 4]);
    const float4 bb = *reinterpret_cast<const float4*>(&b[q * 4]);

    float4 r;
    r.x = 0.5f * (a.x + c.x) + bb.x;
    r.y = 0.5f * (a.y + c.y) + bb.y;
    r.z = 0.5f * (a.z + c.z) + bb.z;
    r.w = 0.5f * (a.w + c.w) + bb.w;

    *reinterpret_cast<float4*>(&out[(size_t)e * F + q * 4]) = r;
}

extern "C" void kernel_launch(void* const* d_in, const int* in_sizes, int n_in,
                              void* d_out, int out_size, void* d_ws, size_t ws_size,
                              hipStream_t stream) {
    const float* inputs = (const float*)d_in[0];
    const int*   src    = (const int*)d_in[1];
    const int*   dst    = (const int*)d_in[2];
    const float* W      = (const float*)d_in[3];
    const float* b      = (const float*)d_in[4];
    float* out = (float*)d_out;

    // Workspace layout
    int* bhist      = (int*)d_ws;                        // NB
    int* bucket_off = bhist + NB;                        // NB+1
    int* cursor     = bucket_off + NB + 1;               // NB
    int* coarse     = cursor + NB;                       // E
    int* eid        = coarse + N_EDGES;                  // E
    int* src_sorted = eid + N_EDGES;                     // E
    int* row_off    = src_sorted + N_EDGES;              // N+1
    float* node_mean = (float*)(row_off + N_NODES + 1);  // N*F
    float* node_h    = node_mean + (size_t)N_NODES * F;  // N*F
    float* node_p    = node_mean;   // alias: node_mean dead after k_node_h

    hipMemsetAsync(bhist, 0, NB * sizeof(int), stream);

    k_bhist<<<256, 256, 0, stream>>>(dst, bhist);
    k_bscan<<<1, 512, 0, stream>>>(bhist, bucket_off, cursor);
    k_coarse_fill<<<(N_EDGES + FILL_CHUNK - 1) / FILL_CHUNK, 256, 0, stream>>>(
        dst, cursor, coarse);
    k_exact_fill<<<NB, 256, 0, stream>>>(
        coarse, bucket_off, src, row_off, eid, src_sorted);

    int node_blocks = (N_NODES + 3) / 4;   // 1 wave per node, 4 waves/block
    k_node_mean<<<node_blocks, 256, 0, stream>>>(inputs, eid, row_off, node_mean);
    k_node_h<<<node_blocks, 256, 0, stream>>>(src_sorted, row_off, node_mean, node_h);

    k_project<<<(N_NODES + 7) / 8, 256, 0, stream>>>(node_h, W, node_p);
    k_edge_out<<<(N_EDGES * 8 + 255) / 256, 256, 0, stream>>>(src, dst, node_p, b, out);
}

// Round 6
// 255.380 us; speedup vs baseline: 3.2674x; 1.1285x over previous
//
#include <hip/hip_runtime.h>

#define N_NODES 50000
#define N_EDGES 1600000
#define F 32
#define BSH 7                               // 128 nodes per bucket
#define BSIZE (1 << BSH)
#define NB ((N_NODES + BSIZE - 1) >> BSH)   // 391 buckets
#define FILL_CHUNK 8192
#define EMASK 0x1FFFFF

// ---------- coarse bucket histogram (LDS-privatized) ----------
__global__ __launch_bounds__(256)
void k_bhist(const int* __restrict__ dst, int* __restrict__ bhist) {
    __shared__ int lh[NB];
    for (int i = threadIdx.x; i < NB; i += 256) lh[i] = 0;
    __syncthreads();
    for (int e = blockIdx.x * blockDim.x + threadIdx.x; e < N_EDGES;
         e += gridDim.x * blockDim.x)
        atomicAdd(&lh[dst[e] >> BSH], 1);
    __syncthreads();
    for (int i = threadIdx.x; i < NB; i += 256)
        if (lh[i]) atomicAdd(&bhist[i], lh[i]);
}

// ---------- scan 391 bucket counts -> offsets + fill cursors ----------
__global__ __launch_bounds__(512)
void k_bscan(const int* __restrict__ bhist,
             int* __restrict__ bucket_off,
             int* __restrict__ cursor) {
    __shared__ int s[512];
    int t = threadIdx.x;
    int v = (t < NB) ? bhist[t] : 0;
    s[t] = v;
    __syncthreads();
    for (int off = 1; off < 512; off <<= 1) {
        int u = (t >= off) ? s[t - off] : 0;
        __syncthreads();
        s[t] += u;
        __syncthreads();
    }
    if (t < NB) {
        int ex = s[t] - v;
        bucket_off[t] = ex;
        cursor[t] = ex;
    }
    if (t == NB - 1) bucket_off[NB] = s[t];
}

// ---------- phase A: bin edges into bucket runs; carry src coalesced ----------
__global__ __launch_bounds__(256)
void k_coarse_fill(const int* __restrict__ dst,
                   const int* __restrict__ src,
                   int* __restrict__ cursor,
                   int2* __restrict__ coarse2) {
    __shared__ int lh[NB];
    __shared__ int gb[NB];
    int lo = blockIdx.x * FILL_CHUNK;
    int hi = min(lo + FILL_CHUNK, N_EDGES);

    for (int i = threadIdx.x; i < NB; i += 256) lh[i] = 0;
    __syncthreads();
    for (int e = lo + threadIdx.x; e < hi; e += 256)
        atomicAdd(&lh[dst[e] >> BSH], 1);
    __syncthreads();
    for (int i = threadIdx.x; i < NB; i += 256) {
        gb[i] = atomicAdd(&cursor[i], lh[i]);
        lh[i] = 0;                  // reuse as rank counter
    }
    __syncthreads();
    for (int e = lo + threadIdx.x; e < hi; e += 256) {
        int d = dst[e];
        int bk = d >> BSH;
        int r = atomicAdd(&lh[bk], 1);
        int2 v;
        v.x = e | ((d & (BSIZE - 1)) << 21);   // e < 2^21
        v.y = src[e];                          // coalesced read here
        coarse2[gb[bk] + r] = v;
    }
}

// ---------- phase B: exact CSR within each 128-node bucket ----------
// All reads sequential; scattered writes land in this block's ~512KB window.
__global__ __launch_bounds__(256)
void k_exact_fill(const int2* __restrict__ coarse2,
                  const int* __restrict__ bucket_off,
                  int* __restrict__ row_off,
                  int* __restrict__ eid_sorted,
                  int* __restrict__ src_sorted) {
    __shared__ int cnt[BSIZE];
    __shared__ int s[BSIZE];
    __shared__ int cur[BSIZE];
    int tid = threadIdx.x;
    int b = blockIdx.x;
    int lo = bucket_off[b], hi = bucket_off[b + 1];

    if (tid < BSIZE) cnt[tid] = 0;
    __syncthreads();
    for (int i = lo + tid; i < hi; i += 256)
        atomicAdd(&cnt[(coarse2[i].x >> 21) & (BSIZE - 1)], 1);
    __syncthreads();
    if (tid < BSIZE) s[tid] = cnt[tid];
    __syncthreads();
    for (int off = 1; off < BSIZE; off <<= 1) {
        int v = 0;
        if (tid < BSIZE && tid >= off) v = s[tid - off];
        __syncthreads();
        if (tid < BSIZE) s[tid] += v;
        __syncthreads();
    }
    int nbase = b << BSH;
    if (tid < BSIZE) {
        int base = lo + s[tid] - cnt[tid];   // exclusive scan + bucket base
        cur[tid] = base;
        if (nbase + tid < N_NODES) row_off[nbase + tid] = base;
    }
    if (b == NB - 1 && tid == 0) row_off[N_NODES] = N_EDGES;
    __syncthreads();
    for (int i = lo + tid; i < hi; i += 256) {
        int2 v = coarse2[i];
        int l = (v.x >> 21) & (BSIZE - 1);
        int p = atomicAdd(&cur[l], 1);
        eid_sorted[p] = v.x & EMASK;
        src_sorted[p] = v.y;
    }
}

// ---------- stage 1+2: node_mean via per-node wave reduce (no atomics) ----------
__global__ __launch_bounds__(256)
void k_node_mean(const float* __restrict__ inputs,
                 const int* __restrict__ eid_sorted,
                 const int* __restrict__ row_off,
                 float* __restrict__ node_mean) {
    int wave = (blockIdx.x * blockDim.x + threadIdx.x) >> 6;
    if (wave >= N_NODES) return;
    int lane  = threadIdx.x & 63;
    int eslot = lane >> 3;       // 0..7
    int q     = lane & 7;        // float4 quad

    int s0 = row_off[wave];
    int s1 = row_off[wave + 1];

    float4 acc = {0.f, 0.f, 0.f, 0.f};
    for (int i = s0 + eslot; i < s1; i += 8) {
        int e = eid_sorted[i];
        float4 v = *reinterpret_cast<const float4*>(&inputs[(size_t)e * F + q * 4]);
        acc.x += v.x; acc.y += v.y; acc.z += v.z; acc.w += v.w;
    }
    #pragma unroll
    for (int m = 8; m <= 32; m <<= 1) {
        acc.x += __shfl_xor(acc.x, m);
        acc.y += __shfl_xor(acc.y, m);
        acc.z += __shfl_xor(acc.z, m);
        acc.w += __shfl_xor(acc.w, m);
    }
    if (eslot == 0) {
        float r = 1.0f / fmaxf((float)(s1 - s0), 1.0f);
        float4 o = {acc.x * r, acc.y * r, acc.z * r, acc.w * r};
        *reinterpret_cast<float4*>(&node_mean[(size_t)wave * F + q * 4]) = o;
    }
}

// ---------- stage 3 + projection fused: node_p = (sum mean[src]) @ W^T ----------
// 4 waves = 4 nodes per block; reduce result staged in LDS, projected in epilogue.
__global__ __launch_bounds__(256)
void k_node_h_project(const int* __restrict__ src_sorted,
                      const int* __restrict__ row_off,
                      const float* __restrict__ node_mean,
                      const float* __restrict__ W,
                      float* __restrict__ node_p) {
    __shared__ float Wl[32][33];
    __shared__ float hr[4][36];   // stride 36: float4-aligned rows

    int tid = threadIdx.x;
    #pragma unroll
    for (int i = tid; i < 1024; i += 256) Wl[i >> 5][i & 31] = W[i];

    int wv    = tid >> 6;        // wave 0..3 = local node
    int lane  = tid & 63;
    int eslot = lane >> 3;
    int q     = lane & 7;
    int n     = blockIdx.x * 4 + wv;     // N_NODES = 12500*4, no tail

    int s0 = row_off[n];
    int s1 = row_off[n + 1];

    float4 acc = {0.f, 0.f, 0.f, 0.f};
    for (int i = s0 + eslot; i < s1; i += 8) {
        int s = src_sorted[i];
        float4 v = *reinterpret_cast<const float4*>(&node_mean[(size_t)s * F + q * 4]);
        acc.x += v.x; acc.y += v.y; acc.z += v.z; acc.w += v.w;
    }
    #pragma unroll
    for (int m = 8; m <= 32; m <<= 1) {
        acc.x += __shfl_xor(acc.x, m);
        acc.y += __shfl_xor(acc.y, m);
        acc.z += __shfl_xor(acc.z, m);
        acc.w += __shfl_xor(acc.w, m);
    }
    if (eslot == 0) {
        *reinterpret_cast<float4*>(&hr[wv][q * 4]) = acc;
    }
    __syncthreads();

    if (tid < 128) {
        int ln = tid >> 5;       // local node
        int o  = tid & 31;       // output channel
        float sacc = 0.f;
        #pragma unroll
        for (int i = 0; i < 32; ++i) sacc += hr[ln][i] * Wl[o][i];
        node_p[(size_t)(blockIdx.x * 4 + ln) * F + o] = sacc;
    }
}

// ---------- stage 4: out[e] = 0.5*(node_p[src] + node_p[dst]) + b ----------
__global__ void k_edge_out(const int* __restrict__ src,
                           const int* __restrict__ dst,
                           const float* __restrict__ node_p,
                           const float* __restrict__ b,
                           float* __restrict__ out) {
    int tid = blockIdx.x * blockDim.x + threadIdx.x;   // e*8 + q
    if (tid >= N_EDGES * 8) return;
    int e = tid >> 3;
    int q = tid & 7;
    int s = src[e];
    int d = dst[e];

    const float4 a  = *reinterpret_cast<const float4*>(&node_p[(size_t)s * F + q * 4]);
    const float4 c  = *reinterpret_cast<const float4*>(&node_p[(size_t)d * F + q * 4]);
    const float4 bb = *reinterpret_cast<const float4*>(&b[q * 4]);

    float4 r;
    r.x = 0.5f * (a.x + c.x) + bb.x;
    r.y = 0.5f * (a.y + c.y) + bb.y;
    r.z = 0.5f * (a.z + c.z) + bb.z;
    r.w = 0.5f * (a.w + c.w) + bb.w;

    *reinterpret_cast<float4*>(&out[(size_t)e * F + q * 4]) = r;
}

extern "C" void kernel_launch(void* const* d_in, const int* in_sizes, int n_in,
                              void* d_out, int out_size, void* d_ws, size_t ws_size,
                              hipStream_t stream) {
    const float* inputs = (const float*)d_in[0];
    const int*   src    = (const int*)d_in[1];
    const int*   dst    = (const int*)d_in[2];
    const float* W      = (const float*)d_in[3];
    const float* b      = (const float*)d_in[4];
    float* out = (float*)d_out;

    // Workspace layout (16B-aligned floats first, then int2, then ints)
    float* node_mean = (float*)d_ws;                       // N*F
    float* node_p    = node_mean + (size_t)N_NODES * F;    // N*F (distinct: fused
                                                           // kernel reads node_mean
                                                           // while writing node_p)
    int2* coarse2    = (int2*)(node_p + (size_t)N_NODES * F);  // E
    int*  bhist      = (int*)(coarse2 + N_EDGES);          // NB
    int*  bucket_off = bhist + NB;                         // NB+1
    int*  cursor     = bucket_off + NB + 1;                // NB
    int*  row_off    = cursor + NB;                        // N+1
    int*  eid_sorted = row_off + N_NODES + 1;              // E
    int*  src_sorted = eid_sorted + N_EDGES;               // E

    hipMemsetAsync(bhist, 0, NB * sizeof(int), stream);

    k_bhist<<<256, 256, 0, stream>>>(dst, bhist);
    k_bscan<<<1, 512, 0, stream>>>(bhist, bucket_off, cursor);
    k_coarse_fill<<<(N_EDGES + FILL_CHUNK - 1) / FILL_CHUNK, 256, 0, stream>>>(
        dst, src, cursor, coarse2);
    k_exact_fill<<<NB, 256, 0, stream>>>(
        coarse2, bucket_off, row_off, eid_sorted, src_sorted);

    int node_blocks = (N_NODES + 3) / 4;   // 1 wave per node, 4 waves/block
    k_node_mean<<<node_blocks, 256, 0, stream>>>(inputs, eid_sorted, row_off, node_mean);
    k_node_h_project<<<N_NODES / 4, 256, 0, stream>>>(
        src_sorted, row_off, node_mean, W, node_p);
    k_edge_out<<<(N_EDGES * 8 + 255) / 256, 256, 0, stream>>>(src, dst, node_p, b, out);
}